// Round 1
// baseline (1796.794 us; speedup 1.0000x reference)
//
#include <hip/hip_runtime.h>

// GATRotationRegressor fused kernel — fp32 correctness-first baseline.
// One workgroup (256 threads) per batch element; whole 24-joint graph in LDS.
//
// Shapes: B=16384, J=24, IN=3, H=128, HEADS=4, C=32, OUT=6, L=3.

#define J 24
#define H 128
#define STR 132   // LDS row stride (pad 128->132: breaks bank aliasing, keeps 16B align)
#define YSTR 66   // y1 buffer stride (64->66)

// incoming edges per destination joint: {parent} u {children} u {self}
__constant__ int c_deg[J] = {4,3,3,3,3,3,3,3,3,5,2,2,3,3,3,2,3,3,3,3,3,3,2,2};
__constant__ int c_inc[J][5] = {
  {1,2,3,0,0},   // 0: children 1,2,3 + self
  {0,4,1,0,0},   // 1
  {0,5,2,0,0},   // 2
  {0,6,3,0,0},   // 3
  {1,7,4,0,0},   // 4
  {2,8,5,0,0},   // 5
  {3,9,6,0,0},   // 6
  {4,10,7,0,0},  // 7
  {5,11,8,0,0},  // 8
  {6,12,13,14,9},// 9
  {7,10,0,0,0},  // 10
  {8,11,0,0,0},  // 11
  {9,15,12,0,0}, // 12
  {9,16,13,0,0}, // 13
  {9,17,14,0,0}, // 14
  {12,15,0,0,0}, // 15
  {13,18,16,0,0},// 16
  {14,19,17,0,0},// 17
  {16,20,18,0,0},// 18
  {17,21,19,0,0},// 19
  {18,22,20,0,0},// 20
  {19,23,21,0,0},// 21
  {20,22,0,0,0}, // 22
  {21,23,0,0,0}  // 23
};

__global__ __launch_bounds__(256) void gat_fused(
    const float* __restrict__ x,     const float* __restrict__ in_w,  const float* __restrict__ in_b,
    const float* __restrict__ res_w, const float* __restrict__ res_b, const float* __restrict__ pos,
    const float* __restrict__ gat_w, const float* __restrict__ att_s, const float* __restrict__ att_d,
    const float* __restrict__ gat_b, const float* __restrict__ ln_g,  const float* __restrict__ ln_b,
    const float* __restrict__ w1,    const float* __restrict__ b1,
    const float* __restrict__ lng2,  const float* __restrict__ lnb2,
    const float* __restrict__ w2,    const float* __restrict__ b2,
    float* __restrict__ out)
{
  __shared__ __align__(16) float s_h [J*STR];  // node features
  __shared__ __align__(16) float s_xl[J*STR];  // h @ gat_w
  __shared__ __align__(16) float s_ob[J*STR];  // post-elu aggregation
  __shared__ __align__(16) float s_y [J*YSTR]; // relu(h@w1+b1)
  __shared__ float s_x[J*3];
  __shared__ float s_asd[J*4*2];               // (a_s, a_d) per (joint, head)
  __shared__ float s_alp[J*5*4];               // alpha per (dst, slot, head)
  __shared__ float s_mr[J*2];                  // (mean, rstd) per joint

  const int tid = threadIdx.x;
  const int b   = blockIdx.x;
  const int n   = tid & 127;    // channel
  const int jb  = tid >> 7;     // 0..1 -> joints jb, jb+2, ..., jb+22
  const int hd  = n >> 5;       // head of this channel

  // ---- stage x into LDS ----
  if (tid < J*3) s_x[tid] = x[b*(J*3) + tid];
  __syncthreads();

  // ---- input projection: h = x@in_w + in_b + pos ; res = x@res_w + res_b ----
  float rg[12];
  {
    const float iw0 = in_w[n],  iw1 = in_w[128+n],  iw2 = in_w[256+n],  ib = in_b[n];
    const float rw0 = res_w[n], rw1 = res_w[128+n], rw2 = res_w[256+n], rb = res_b[n];
#pragma unroll
    for (int i = 0; i < 12; ++i) {
      const int j = jb + 2*i;
      const float x0 = s_x[j*3], x1 = s_x[j*3+1], x2 = s_x[j*3+2];
      s_h[j*STR+n] = x0*iw0 + x1*iw1 + x2*iw2 + ib + pos[j*128+n];
      rg[i]        = x0*rw0 + x1*rw1 + x2*rw2 + rb;
    }
  }
  __syncthreads();

  // ---- GAT layers ----
  for (int l = 0; l < 3; ++l) {
    // xl = h @ gat_w[l]   (W element loaded once, reused for 12 joints)
    {
      const float* __restrict__ W = gat_w + l*128*128;
      float acc[12];
#pragma unroll
      for (int i = 0; i < 12; ++i) acc[i] = 0.f;
      for (int k0 = 0; k0 < 128; k0 += 4) {
        const float w0 = W[(k0+0)*128+n];
        const float w1v= W[(k0+1)*128+n];
        const float w2v= W[(k0+2)*128+n];
        const float w3v= W[(k0+3)*128+n];
#pragma unroll
        for (int i = 0; i < 12; ++i) {
          const int j = jb + 2*i;
          const float4 hv = *(const float4*)&s_h[j*STR + k0]; // wave-uniform broadcast
          acc[i] += hv.x*w0 + hv.y*w1v + hv.z*w2v + hv.w*w3v;
        }
      }
#pragma unroll
      for (int i = 0; i < 12; ++i) s_xl[(jb+2*i)*STR + n] = acc[i];
    }
    __syncthreads();

    // attention logits a_s, a_d per (joint, head)
    if (tid < 96) {
      const int j = tid >> 2, hh = tid & 3;
      const float* __restrict__ ws = att_s + (l*4+hh)*32;
      const float* __restrict__ wd = att_d + (l*4+hh)*32;
      float sa = 0.f, sd = 0.f;
#pragma unroll 8
      for (int c = 0; c < 32; ++c) {
        const float v = s_xl[j*STR + hh*32 + c];
        sa += v * ws[c];
        sd += v * wd[c];
      }
      s_asd[(j*4+hh)*2+0] = sa;
      s_asd[(j*4+hh)*2+1] = sd;
    }
    __syncthreads();

    // scatter-softmax alpha per (dst, incoming slot, head)
    if (tid < 96) {
      const int j = tid >> 2, hh = tid & 3;
      const int dg = c_deg[j];
      const float ad = s_asd[(j*4+hh)*2+1];
      float ev[5];
      float m = -1e30f;
#pragma unroll
      for (int i = 0; i < 5; ++i) if (i < dg) {
        float e = s_asd[(c_inc[j][i]*4+hh)*2+0] + ad;
        e = (e >= 0.f) ? e : 0.2f*e;          // leaky_relu slope 0.2
        ev[i] = e;
        m = fmaxf(m, e);
      }
      float den = 0.f;
#pragma unroll
      for (int i = 0; i < 5; ++i) if (i < dg) { ev[i] = __expf(ev[i]-m); den += ev[i]; }
      const float inv = 1.f/den;
#pragma unroll
      for (int i = 0; i < 5; ++i) if (i < dg) s_alp[(j*5+i)*4+hh] = ev[i]*inv;
    }
    __syncthreads();

    // aggregate messages, add bias, elu
    {
      const float gb = gat_b[l*128+n];
#pragma unroll
      for (int i = 0; i < 12; ++i) {
        const int j = jb + 2*i;
        const int dg = c_deg[j];
        float a = gb;
#pragma unroll
        for (int e = 0; e < 5; ++e) if (e < dg) {
          a += s_alp[(j*5+e)*4+hd] * s_xl[c_inc[j][e]*STR + n];
        }
        a = (a > 0.f) ? a : (__expf(a) - 1.f);  // elu
        s_ob[j*STR+n] = a;
      }
    }
    __syncthreads();

    // LN stats over H=128 per joint (8 lanes per joint)
    if (tid < 192) {
      const int j = tid >> 3, lg = tid & 7;
      float s = 0.f, s2 = 0.f;
#pragma unroll
      for (int t = 0; t < 16; ++t) {
        const float v = s_ob[j*STR + lg + 8*t];
        s += v; s2 += v*v;
      }
#pragma unroll
      for (int off = 1; off < 8; off <<= 1) {
        s  += __shfl_xor(s,  off, 64);
        s2 += __shfl_xor(s2, off, 64);
      }
      if (lg == 0) {
        const float mean = s * (1.f/128.f);
        const float var  = s2 * (1.f/128.f) - mean*mean;
        s_mr[j*2+0] = mean;
        s_mr[j*2+1] = rsqrtf(var + 1e-5f);
      }
    }
    __syncthreads();

    // apply LN (+ residual for l>0); becomes new h
    {
      const float g = ln_g[l*128+n], bb = ln_b[l*128+n];
#pragma unroll
      for (int i = 0; i < 12; ++i) {
        const int j = jb + 2*i;
        float v = (s_ob[j*STR+n] - s_mr[j*2]) * s_mr[j*2+1] * g + bb;
        if (l > 0) v += s_h[j*STR+n];
        s_h[j*STR+n] = v;
      }
    }
    __syncthreads();
  }

  // ---- h += res ----
#pragma unroll
  for (int i = 0; i < 12; ++i) s_h[(jb+2*i)*STR+n] += rg[i];
  __syncthreads();

  // ---- y1 = relu(h @ w1 + b1), [24,64] ----
  {
    const int m = tid & 63, jb4 = tid >> 6;  // 6 joints per thread, stride 4
    float acc1[6];
    const float bm = b1[m];
#pragma unroll
    for (int i = 0; i < 6; ++i) acc1[i] = bm;
    for (int k0 = 0; k0 < 128; k0 += 4) {
      const float a0 = w1[(k0+0)*64+m];
      const float a1 = w1[(k0+1)*64+m];
      const float a2 = w1[(k0+2)*64+m];
      const float a3 = w1[(k0+3)*64+m];
#pragma unroll
      for (int i = 0; i < 6; ++i) {
        const int j = jb4 + 4*i;
        const float4 hv = *(const float4*)&s_h[j*STR + k0];
        acc1[i] += hv.x*a0 + hv.y*a1 + hv.z*a2 + hv.w*a3;
      }
    }
#pragma unroll
    for (int i = 0; i < 6; ++i) s_y[(jb4+4*i)*YSTR + m] = fmaxf(acc1[i], 0.f);
  }
  __syncthreads();

  // ---- LN over 64 per joint ----
  if (tid < 192) {
    const int j = tid >> 3, lg = tid & 7;
    float s = 0.f, s2 = 0.f;
#pragma unroll
    for (int t = 0; t < 8; ++t) {
      const float v = s_y[j*YSTR + lg + 8*t];
      s += v; s2 += v*v;
    }
#pragma unroll
    for (int off = 1; off < 8; off <<= 1) {
      s  += __shfl_xor(s,  off, 64);
      s2 += __shfl_xor(s2, off, 64);
    }
    if (lg == 0) {
      const float mean = s * (1.f/64.f);
      const float var  = s2 * (1.f/64.f) - mean*mean;
      s_mr[j*2+0] = mean;
      s_mr[j*2+1] = rsqrtf(var + 1e-5f);
    }
  }
  __syncthreads();

  // ---- out = LN(y1) @ w2 + b2, [24,6] ----
  if (tid < 144) {
    const int j = tid / 6, o = tid - j*6;
    const float mean = s_mr[j*2], rstd = s_mr[j*2+1];
    float acc = b2[o];
#pragma unroll 8
    for (int m = 0; m < 64; ++m) {
      const float yv = (s_y[j*YSTR+m] - mean) * rstd * lng2[m] + lnb2[m];
      acc += yv * w2[m*6+o];
    }
    out[b*144 + tid] = acc;
  }
}

extern "C" void kernel_launch(void* const* d_in, const int* in_sizes, int n_in,
                              void* d_out, int out_size, void* d_ws, size_t ws_size,
                              hipStream_t stream) {
  (void)n_in; (void)d_ws; (void)ws_size; (void)out_size;
  const float* x     = (const float*)d_in[0];
  const float* in_w  = (const float*)d_in[1];
  const float* in_b  = (const float*)d_in[2];
  const float* res_w = (const float*)d_in[3];
  const float* res_b = (const float*)d_in[4];
  const float* pos   = (const float*)d_in[5];
  const float* gat_w = (const float*)d_in[6];
  const float* att_s = (const float*)d_in[7];
  const float* att_d = (const float*)d_in[8];
  const float* gat_b = (const float*)d_in[9];
  const float* ln_g  = (const float*)d_in[10];
  const float* ln_b  = (const float*)d_in[11];
  const float* w1    = (const float*)d_in[12];
  const float* b1    = (const float*)d_in[13];
  const float* lng2  = (const float*)d_in[14];
  const float* lnb2  = (const float*)d_in[15];
  const float* w2    = (const float*)d_in[16];
  const float* b2    = (const float*)d_in[17];
  float* out = (float*)d_out;

  const int B = in_sizes[0] / (J*3);
  hipLaunchKernelGGL(gat_fused, dim3(B), dim3(256), 0, stream,
                     x, in_w, in_b, res_w, res_b, pos, gat_w, att_s, att_d,
                     gat_b, ln_g, ln_b, w1, b1, lng2, lnb2, w2, b2, out);
}

// Round 2
// 1338.807 us; speedup vs baseline: 1.3421x; 1.3421x over previous
//
#include <hip/hip_runtime.h>

// GATRotationRegressor — round 2: bf16 MFMA for the H×H matmuls + FFN.
// One workgroup (256 threads) per batch element; whole 24-joint graph in LDS.
// Shapes: B=16384, J=24, IN=3, H=128, HEADS=4, C=32, OUT=6, L=3.

#define J 24
#define H 128
#define STR 132    // fp32 LDS row stride
#define HBSTR 136  // bf16 LDS row stride (272B: 16B-aligned, rows spread over banks)

typedef __attribute__((ext_vector_type(8))) short short8;
typedef __attribute__((ext_vector_type(4))) float f32x4;

// incoming edges per destination joint: {parent} u {children} u {self}
__constant__ int c_deg[J] = {4,3,3,3,3,3,3,3,3,5,2,2,3,3,3,2,3,3,3,3,3,3,2,2};
__constant__ int c_inc[J][5] = {
  {1,2,3,0,0},{0,4,1,0,0},{0,5,2,0,0},{0,6,3,0,0},{1,7,4,0,0},{2,8,5,0,0},
  {3,9,6,0,0},{4,10,7,0,0},{5,11,8,0,0},{6,12,13,14,9},{7,10,0,0,0},{8,11,0,0,0},
  {9,15,12,0,0},{9,16,13,0,0},{9,17,14,0,0},{12,15,0,0,0},{13,18,16,0,0},{14,19,17,0,0},
  {16,20,18,0,0},{17,21,19,0,0},{18,22,20,0,0},{19,23,21,0,0},{20,22,0,0,0},{21,23,0,0,0}
};

__device__ __forceinline__ unsigned short f2bf(float f) {
  unsigned u = __builtin_bit_cast(unsigned, f);
  u = (u + 0x7FFFu + ((u >> 16) & 1u)) >> 16;   // RNE
  return (unsigned short)u;
}

// Pre-pass: Wt[l][n][k] = bf16(gat_w[l][k][n]) at ws[0..49152);
//           w1t[m][k]   = bf16(w1[k][m])       at ws[49152..57344).
__global__ __launch_bounds__(256) void prep_weights(
    const float* __restrict__ gat_w, const float* __restrict__ w1,
    unsigned short* __restrict__ ws)
{
  const int idx = blockIdx.x * 256 + threadIdx.x;
  if (idx < 3*128*128) {
    const int l = idx >> 14, rem = idx & 16383;
    const int n = rem >> 7, k = rem & 127;
    ws[idx] = f2bf(gat_w[l*16384 + k*128 + n]);
  } else if (idx < 3*128*128 + 64*128) {
    const int i2 = idx - 3*128*128;
    const int m = i2 >> 7, k = i2 & 127;
    ws[idx] = f2bf(w1[k*64 + m]);
  }
}

template<bool USE_WS>
__global__ __launch_bounds__(256) void gat_fused(
    const float* __restrict__ x,     const float* __restrict__ in_w,  const float* __restrict__ in_b,
    const float* __restrict__ res_w, const float* __restrict__ res_b, const float* __restrict__ pos,
    const float* __restrict__ gat_w, const float* __restrict__ att_s, const float* __restrict__ att_d,
    const float* __restrict__ gat_b, const float* __restrict__ ln_g,  const float* __restrict__ ln_b,
    const float* __restrict__ w1,    const float* __restrict__ b1,
    const float* __restrict__ lng2,  const float* __restrict__ lnb2,
    const float* __restrict__ w2,    const float* __restrict__ b2,
    const unsigned short* __restrict__ wt,   // bf16 Wt (valid iff USE_WS)
    float* __restrict__ out)
{
  __shared__ __align__(16) float s_h[J*STR];          // master h, fp32
  __shared__ __align__(16) float s_xl[32*STR];        // h@W result (also y1 later)
  __shared__ __align__(16) unsigned char s_u[J*STR*4];// union: s_ob fp32 [24][STR] / s_hb bf16 [32][HBSTR]
  __shared__ float s_x[J*3];
  __shared__ float s_asd[J*4*2];
  __shared__ float s_alp[J*5*4];
  __shared__ float s_mr[J*2];

  float* s_ob = (float*)s_u;
  unsigned short* s_hb = (unsigned short*)s_u;
  float* s_y = s_xl;   // FFN reuses xl buffer

  const int tid = threadIdx.x;
  const int b   = blockIdx.x;
  const int n   = tid & 127;
  const int jb  = tid >> 7;       // joints jb, jb+2, ..., jb+22
  const int hd  = n >> 5;

  const int w    = tid >> 6;      // wave id 0..3
  const int lane = tid & 63;
  const int l16  = lane & 15;
  const int q    = lane >> 4;     // quad 0..3

  // ---- stage x ----
  if (tid < J*3) s_x[tid] = x[b*(J*3) + tid];
  __syncthreads();

  // ---- input projection ----
  float rg[12];
  {
    const float iw0 = in_w[n],  iw1 = in_w[128+n],  iw2 = in_w[256+n],  ib = in_b[n];
    const float rw0 = res_w[n], rw1 = res_w[128+n], rw2 = res_w[256+n], rb = res_b[n];
#pragma unroll
    for (int i = 0; i < 12; ++i) {
      const int j = jb + 2*i;
      const float x0 = s_x[j*3], x1 = s_x[j*3+1], x2 = s_x[j*3+2];
      const float hv = x0*iw0 + x1*iw1 + x2*iw2 + ib + pos[j*128+n];
      s_h[j*STR+n]    = hv;
      s_hb[j*HBSTR+n] = f2bf(hv);
      rg[i]           = x0*rw0 + x1*rw1 + x2*rw2 + rb;
    }
  }
  __syncthreads();

  // ---- GAT layers ----
  for (int l = 0; l < 3; ++l) {
    // === xl = h @ gat_w[l] via MFMA (M=32 padded, N=128, K=128) ===
    {
      const int mt  = w & 1;            // M-tile
      const int ntb = (w >> 1) * 4;     // first of 4 N-tiles
      const int row_a = mt*16 + l16;
      f32x4 acc[4] = { {0,0,0,0}, {0,0,0,0}, {0,0,0,0}, {0,0,0,0} };
#pragma unroll
      for (int ks = 0; ks < 4; ++ks) {
        const short8 a = *(const short8*)&s_hb[row_a*HBSTR + ks*32 + q*8];
#pragma unroll
        for (int t = 0; t < 4; ++t) {
          short8 bfr;
          if constexpr (USE_WS) {
            bfr = *(const short8*)&wt[(l*128 + (ntb+t)*16 + l16)*128 + ks*32 + q*8];
          } else {
            union { short8 v; unsigned short u[8]; } bu;
            const float* Wp = gat_w + l*16384 + (ks*32 + q*8)*128 + (ntb+t)*16 + l16;
#pragma unroll
            for (int jj = 0; jj < 8; ++jj) bu.u[jj] = f2bf(Wp[jj*128]);
            bfr = bu.v;
          }
          acc[t] = __builtin_amdgcn_mfma_f32_16x16x32_bf16(a, bfr, acc[t], 0, 0, 0);
        }
      }
#pragma unroll
      for (int t = 0; t < 4; ++t) {
        const int col = (ntb+t)*16 + l16;
#pragma unroll
        for (int r = 0; r < 4; ++r) {
          const int row = mt*16 + q*4 + r;
          s_xl[row*STR + col] = acc[t][r];
        }
      }
    }
    __syncthreads();

    // === attention logits ===
    if (tid < 96) {
      const int j = tid >> 2, hh = tid & 3;
      const float* __restrict__ wsrc = att_s + (l*4+hh)*32;
      const float* __restrict__ wdst = att_d + (l*4+hh)*32;
      float sa = 0.f, sd = 0.f;
#pragma unroll 8
      for (int c = 0; c < 32; ++c) {
        const float v = s_xl[j*STR + hh*32 + c];
        sa += v * wsrc[c];
        sd += v * wdst[c];
      }
      s_asd[(j*4+hh)*2+0] = sa;
      s_asd[(j*4+hh)*2+1] = sd;
    }
    __syncthreads();

    // === scatter-softmax ===
    if (tid < 96) {
      const int j = tid >> 2, hh = tid & 3;
      const int dg = c_deg[j];
      const float ad = s_asd[(j*4+hh)*2+1];
      float ev[5];
      float m = -1e30f;
#pragma unroll
      for (int i = 0; i < 5; ++i) if (i < dg) {
        float e = s_asd[(c_inc[j][i]*4+hh)*2+0] + ad;
        e = (e >= 0.f) ? e : 0.2f*e;
        ev[i] = e;
        m = fmaxf(m, e);
      }
      float den = 0.f;
#pragma unroll
      for (int i = 0; i < 5; ++i) if (i < dg) { ev[i] = __expf(ev[i]-m); den += ev[i]; }
      const float inv = 1.f/den;
#pragma unroll
      for (int i = 0; i < 5; ++i) if (i < dg) s_alp[(j*5+i)*4+hh] = ev[i]*inv;
    }
    __syncthreads();

    // === aggregate + bias + elu -> s_ob ===
    {
      const float gb = gat_b[l*128+n];
#pragma unroll
      for (int i = 0; i < 12; ++i) {
        const int j = jb + 2*i;
        const int dg = c_deg[j];
        float a = gb;
#pragma unroll
        for (int e = 0; e < 5; ++e) if (e < dg) {
          a += s_alp[(j*5+e)*4+hd] * s_xl[c_inc[j][e]*STR + n];
        }
        a = (a > 0.f) ? a : (__expf(a) - 1.f);
        s_ob[j*STR+n] = a;
      }
    }
    __syncthreads();

    // === LN stats ===
    if (tid < 192) {
      const int j = tid >> 3, lg = tid & 7;
      float s = 0.f, s2 = 0.f;
#pragma unroll
      for (int t = 0; t < 16; ++t) {
        const float v = s_ob[j*STR + lg + 8*t];
        s += v; s2 += v*v;
      }
#pragma unroll
      for (int off = 1; off < 8; off <<= 1) {
        s  += __shfl_xor(s,  off, 64);
        s2 += __shfl_xor(s2, off, 64);
      }
      if (lg == 0) {
        const float mean = s * (1.f/128.f);
        const float var  = s2 * (1.f/128.f) - mean*mean;
        s_mr[j*2+0] = mean;
        s_mr[j*2+1] = rsqrtf(var + 1e-5f);
      }
    }
    __syncthreads();

    // === apply LN (+res for l>0) -> new h; bf16 shadow after barrier ===
    float vh[12];
    {
      const float g = ln_g[l*128+n], bb = ln_b[l*128+n];
#pragma unroll
      for (int i = 0; i < 12; ++i) {
        const int j = jb + 2*i;
        float v = (s_ob[j*STR+n] - s_mr[j*2]) * s_mr[j*2+1] * g + bb;
        if (l > 0) v += s_h[j*STR+n];
        s_h[j*STR+n] = v;
        vh[i] = v;
      }
    }
    __syncthreads();   // all s_ob reads done before s_hb (same memory) is written
    if (l < 2) {
#pragma unroll
      for (int i = 0; i < 12; ++i) s_hb[(jb+2*i)*HBSTR+n] = f2bf(vh[i]);
    }
    __syncthreads();
  }

  // ---- h += res; bf16 shadow for FFN ----
#pragma unroll
  for (int i = 0; i < 12; ++i) {
    const int j = jb + 2*i;
    const float v = s_h[j*STR+n] + rg[i];
    s_h[j*STR+n]    = v;
    s_hb[j*HBSTR+n] = f2bf(v);
  }
  __syncthreads();

  // ---- y1 = relu(h @ w1 + b1) via MFMA (M=32 padded, N=64, K=128) ----
  {
    const int mt  = w & 1;
    const int ntb = (w >> 1) * 2;    // 2 N-tiles per wave
    const int row_a = mt*16 + l16;
    f32x4 acc[2];
#pragma unroll
    for (int t = 0; t < 2; ++t) {
      const float bm = b1[(ntb+t)*16 + l16];
      acc[t] = (f32x4){bm, bm, bm, bm};
    }
#pragma unroll
    for (int ks = 0; ks < 4; ++ks) {
      const short8 a = *(const short8*)&s_hb[row_a*HBSTR + ks*32 + q*8];
#pragma unroll
      for (int t = 0; t < 2; ++t) {
        short8 bfr;
        if constexpr (USE_WS) {
          bfr = *(const short8*)&wt[3*128*128 + ((ntb+t)*16 + l16)*128 + ks*32 + q*8];
        } else {
          union { short8 v; unsigned short u[8]; } bu;
          const float* Wp = w1 + (ks*32 + q*8)*64 + (ntb+t)*16 + l16;
#pragma unroll
          for (int jj = 0; jj < 8; ++jj) bu.u[jj] = f2bf(Wp[jj*64]);
          bfr = bu.v;
        }
        acc[t] = __builtin_amdgcn_mfma_f32_16x16x32_bf16(a, bfr, acc[t], 0, 0, 0);
      }
    }
    __syncthreads();   // s_y aliases s_xl; ensure no stale readers (none) — and order writes
#pragma unroll
    for (int t = 0; t < 2; ++t) {
      const int col = (ntb+t)*16 + l16;
#pragma unroll
      for (int r = 0; r < 4; ++r) {
        const int row = mt*16 + q*4 + r;
        s_y[row*STR + col] = fmaxf(acc[t][r], 0.f);
      }
    }
  }
  __syncthreads();

  // ---- LN over 64 per joint ----
  if (tid < 192) {
    const int j = tid >> 3, lg = tid & 7;
    float s = 0.f, s2 = 0.f;
#pragma unroll
    for (int t = 0; t < 8; ++t) {
      const float v = s_y[j*STR + lg + 8*t];
      s += v; s2 += v*v;
    }
#pragma unroll
    for (int off = 1; off < 8; off <<= 1) {
      s  += __shfl_xor(s,  off, 64);
      s2 += __shfl_xor(s2, off, 64);
    }
    if (lg == 0) {
      const float mean = s * (1.f/64.f);
      const float var  = s2 * (1.f/64.f) - mean*mean;
      s_mr[j*2+0] = mean;
      s_mr[j*2+1] = rsqrtf(var + 1e-5f);
    }
  }
  __syncthreads();

  // ---- out = LN(y1) @ w2 + b2 ----
  if (tid < 144) {
    const int j = tid / 6, o = tid - j*6;
    const float mean = s_mr[j*2], rstd = s_mr[j*2+1];
    float acc = b2[o];
#pragma unroll 8
    for (int m = 0; m < 64; ++m) {
      const float yv = (s_y[j*STR+m] - mean) * rstd * lng2[m] + lnb2[m];
      acc += yv * w2[m*6+o];
    }
    out[b*144 + tid] = acc;
  }
}

extern "C" void kernel_launch(void* const* d_in, const int* in_sizes, int n_in,
                              void* d_out, int out_size, void* d_ws, size_t ws_size,
                              hipStream_t stream) {
  (void)n_in; (void)out_size;
  const float* x     = (const float*)d_in[0];
  const float* in_w  = (const float*)d_in[1];
  const float* in_b  = (const float*)d_in[2];
  const float* res_w = (const float*)d_in[3];
  const float* res_b = (const float*)d_in[4];
  const float* pos   = (const float*)d_in[5];
  const float* gat_w = (const float*)d_in[6];
  const float* att_s = (const float*)d_in[7];
  const float* att_d = (const float*)d_in[8];
  const float* gat_b = (const float*)d_in[9];
  const float* ln_g  = (const float*)d_in[10];
  const float* ln_b  = (const float*)d_in[11];
  const float* w1    = (const float*)d_in[12];
  const float* b1    = (const float*)d_in[13];
  const float* lng2  = (const float*)d_in[14];
  const float* lnb2  = (const float*)d_in[15];
  const float* w2    = (const float*)d_in[16];
  const float* b2    = (const float*)d_in[17];
  float* out = (float*)d_out;

  const int B = in_sizes[0] / (J*3);
  const size_t wt_bytes = (size_t)(3*128*128 + 64*128) * sizeof(unsigned short);
  const bool use_ws = (ws_size >= wt_bytes);

  if (use_ws) {
    unsigned short* wt = (unsigned short*)d_ws;
    const int total = 3*128*128 + 64*128;
    hipLaunchKernelGGL(prep_weights, dim3((total + 255)/256), dim3(256), 0, stream,
                       gat_w, w1, wt);
    hipLaunchKernelGGL((gat_fused<true>), dim3(B), dim3(256), 0, stream,
                       x, in_w, in_b, res_w, res_b, pos, gat_w, att_s, att_d,
                       gat_b, ln_g, ln_b, w1, b1, lng2, lnb2, w2, b2, wt, out);
  } else {
    hipLaunchKernelGGL((gat_fused<false>), dim3(B), dim3(256), 0, stream,
                       x, in_w, in_b, res_w, res_b, pos, gat_w, att_s, att_d,
                       gat_b, ln_g, ln_b, w1, b1, lng2, lnb2, w2, b2,
                       (const unsigned short*)nullptr, out);
  }
}

// Round 3
// 672.294 us; speedup vs baseline: 2.6726x; 1.9914x over previous
//
#include <hip/hip_runtime.h>

// GATRotationRegressor — round 3: 4 batch/block, logits fused into GEMM,
// aggregate+LN fused into one barrier-free stage, all matmuls via MFMA.
// B=16384, J=24, IN=3, H=128, HEADS=4, C=32, OUT=6, L=3.

#define J 24
#define BPB 4
#define ROWS 96           // BPB*J
#define HB 136            // bf16 LDS row stride (shorts) = 272 B, 16B-aligned
#define YS 68             // fp32 y row stride (words)    = 272 B

typedef __attribute__((ext_vector_type(8))) short short8;
typedef __attribute__((ext_vector_type(4))) float f32x4;

// Static device scratch for bf16 weights (no hipMalloc, graph-capture safe).
// [0)      Wt[l][n][k]   3*128*128 = 49152   (gat_w transposed)
// [49152)  w1t[m][k]     64*128    = 8192
// [57344)  wa[l][j][k]   3*16*128  = 6144    (j<4: a_s head j; 4..7: a_d head j-4; 8..15: 0)
// [63488)  w2t[o][m]     16*64     = 1024    (o<6 real, else 0)
__device__ unsigned short g_wt[64512];

__constant__ int c_deg[J] = {4,3,3,3,3,3,3,3,3,5,2,2,3,3,3,2,3,3,3,3,3,3,2,2};
__constant__ int c_inc[J][5] = {
  {1,2,3,0,0},{0,4,1,0,0},{0,5,2,0,0},{0,6,3,0,0},{1,7,4,0,0},{2,8,5,0,0},
  {3,9,6,0,0},{4,10,7,0,0},{5,11,8,0,0},{6,12,13,14,9},{7,10,0,0,0},{8,11,0,0,0},
  {9,15,12,0,0},{9,16,13,0,0},{9,17,14,0,0},{12,15,0,0,0},{13,18,16,0,0},{14,19,17,0,0},
  {16,20,18,0,0},{17,21,19,0,0},{18,22,20,0,0},{19,23,21,0,0},{20,22,0,0,0},{21,23,0,0,0}
};

__device__ __forceinline__ unsigned short f2bf(float f) {
  unsigned u = __builtin_bit_cast(unsigned, f);
  u = (u + 0x7FFFu + ((u >> 16) & 1u)) >> 16;   // RNE
  return (unsigned short)u;
}
__device__ __forceinline__ float bf2f(unsigned short u) {
  return __builtin_bit_cast(float, (unsigned)u << 16);
}

__global__ __launch_bounds__(256) void prep_weights(
    const float* __restrict__ gat_w, const float* __restrict__ att_s,
    const float* __restrict__ att_d, const float* __restrict__ w1,
    const float* __restrict__ w2)
{
  const int idx = blockIdx.x * 256 + threadIdx.x;
  if (idx < 49152) {                       // Wt[l][n][k] = gat_w[l][k][n]
    const int l = idx >> 14, rem = idx & 16383, n = rem >> 7, k = rem & 127;
    g_wt[idx] = f2bf(gat_w[l*16384 + k*128 + n]);
  } else if (idx < 57344) {                // w1t[m][k] = w1[k][m]
    const int i2 = idx - 49152, m = i2 >> 7, k = i2 & 127;
    g_wt[idx] = f2bf(w1[k*64 + m]);
  } else if (idx < 63488) {                // wa[l][j][k] = sum_c gat_w[l][k][hh*32+c]*att[sd][l][hh][c]
    const int i2 = idx - 57344;
    const int l = i2 >> 11, r = i2 & 2047, j = r >> 7, k = r & 127;
    float v = 0.f;
    if (j < 8) {
      const int sd = j >> 2, hhh = j & 3;
      const float* av = (sd ? att_d : att_s) + (l*4 + hhh)*32;
      const float* wp = gat_w + l*16384 + k*128 + hhh*32;
#pragma unroll 8
      for (int c = 0; c < 32; ++c) v += wp[c] * av[c];
    }
    g_wt[idx] = f2bf(v);
  } else if (idx < 64512) {                // w2t[o][m] = w2[m][o]
    const int i2 = idx - 63488, o = i2 >> 6, m = i2 & 63;
    g_wt[idx] = f2bf(o < 6 ? w2[m*6 + o] : 0.f);
  }
}

__global__ __launch_bounds__(256) void gat_fused(
    const float* __restrict__ x,     const float* __restrict__ in_w,  const float* __restrict__ in_b,
    const float* __restrict__ res_w, const float* __restrict__ res_b, const float* __restrict__ pos,
    const float* __restrict__ gat_b, const float* __restrict__ ln_g,  const float* __restrict__ ln_b,
    const float* __restrict__ b1,    const float* __restrict__ lng2,  const float* __restrict__ lnb2,
    const float* __restrict__ b2,    float* __restrict__ out)
{
  __shared__ __align__(16) unsigned short s_hb [ROWS*HB];  // h bf16; later yln bf16
  __shared__ __align__(16) unsigned short s_xlb[ROWS*HB];  // xl bf16; later y1 fp32 overlay
  __shared__ float s_x[BPB*J*3];
  __shared__ float s_asd[ROWS*8];     // cols 0..3 a_s, 4..7 a_d
  __shared__ float s_alp[ROWS*5*4];   // alpha per (row, slot, head)

  const int tid = threadIdx.x;
  const int wv = tid >> 6, lane = tid & 63, l16 = lane & 15, q = lane >> 4;
  // elementwise mapping: 8 lanes per row, 16 channels each, 3 rows per thread
  const int g = tid >> 3, c8 = tid & 7, cb = c8 * 16, hh = c8 >> 1;
  int rr[3], rj[3], rb[3];
#pragma unroll
  for (int i = 0; i < 3; ++i) {
    rr[i] = g + 32*i;
    rb[i] = rr[i] / 24;
    rj[i] = rr[i] - 24*rb[i];
  }

  // ---- P0: stage x ----
  {
    const long base = (long)blockIdx.x * (BPB*J*3);
    s_x[tid] = x[base + tid];
    if (tid < 32) s_x[256 + tid] = x[base + 256 + tid];
  }
  __syncthreads();

  // ---- P1: input projection -> vh (fp32 master) + s_hb (bf16) ----
  float vh[3][16];
#pragma unroll
  for (int i = 0; i < 3; ++i) {
    const float* xp = &s_x[rb[i]*72 + rj[i]*3];
    const float x0 = xp[0], x1 = xp[1], x2 = xp[2];
    short8 p0, p1;
#pragma unroll
    for (int c = 0; c < 16; ++c) {
      const int ch = cb + c;
      float v = x0*in_w[ch] + x1*in_w[128+ch] + x2*in_w[256+ch] + in_b[ch] + pos[rj[i]*128+ch];
      vh[i][c] = v;
      if (c < 8) p0[c] = (short)f2bf(v); else p1[c-8] = (short)f2bf(v);
    }
    *(short8*)&s_hb[rr[i]*HB + cb]     = p0;
    *(short8*)&s_hb[rr[i]*HB + cb + 8] = p1;
  }
  __syncthreads();

  // ---- GAT layers ----
  for (int l = 0; l < 3; ++l) {
    // === L1: MFMA xl = h@W (M=96,N=128,K=128) + fused logits = h@Wa ===
    {
      const unsigned short* Wl = &g_wt[l*16384];
#pragma unroll
      for (int nt2 = 0; nt2 < 2; ++nt2) {
        const int nt = wv*2 + nt2;
        short8 bfr[4];
#pragma unroll
        for (int ks = 0; ks < 4; ++ks)
          bfr[ks] = *(const short8*)&Wl[(nt*16 + l16)*128 + ks*32 + q*8];
        const int col = nt*16 + l16;
#pragma unroll
        for (int mt = 0; mt < 6; ++mt) {
          f32x4 acc = {0.f,0.f,0.f,0.f};
#pragma unroll
          for (int ks = 0; ks < 4; ++ks) {
            const short8 a = *(const short8*)&s_hb[(mt*16 + l16)*HB + ks*32 + q*8];
            acc = __builtin_amdgcn_mfma_f32_16x16x32_bf16(a, bfr[ks], acc, 0, 0, 0);
          }
#pragma unroll
          for (int r = 0; r < 4; ++r)
            s_xlb[(mt*16 + q*4 + r)*HB + col] = f2bf(acc[r]);
        }
      }
      // logit tiles: wave w handles mt = w (+ w+4 for w<2)
      const unsigned short* Wa = &g_wt[57344 + l*2048];
      short8 ba[4];
#pragma unroll
      for (int ks = 0; ks < 4; ++ks)
        ba[ks] = *(const short8*)&Wa[l16*128 + ks*32 + q*8];
      const int nmt = (wv < 2) ? 2 : 1;
#pragma unroll
      for (int s = 0; s < 2; ++s) if (s < nmt) {
        const int mt = wv + 4*s;
        f32x4 acc = {0.f,0.f,0.f,0.f};
#pragma unroll
        for (int ks = 0; ks < 4; ++ks) {
          const short8 a = *(const short8*)&s_hb[(mt*16 + l16)*HB + ks*32 + q*8];
          acc = __builtin_amdgcn_mfma_f32_16x16x32_bf16(a, ba[ks], acc, 0, 0, 0);
        }
        if (l16 < 8) {
#pragma unroll
          for (int r = 0; r < 4; ++r)
            s_asd[(mt*16 + q*4 + r)*8 + l16] = acc[r];
        }
      }
    }
    __syncthreads();

    // === L2: scatter-softmax (384 items = row*4 + head) ===
#pragma unroll
    for (int it = 0; it < 2; ++it) {
      const int item = tid + it*256;
      if (item < 384) {
        const int r = item >> 2, hh2 = item & 3;
        const int bp = r / 24, j = r - 24*bp, base = r - j;
        const int dg = c_deg[j];
        const float ad = s_asd[r*8 + 4 + hh2];
        float ev[5];
        float m = -1e30f;
#pragma unroll
        for (int e = 0; e < 5; ++e) if (e < dg) {
          float ee = s_asd[(base + c_inc[j][e])*8 + hh2] + ad;
          ee = (ee >= 0.f) ? ee : 0.2f*ee;
          ev[e] = ee;
          m = fmaxf(m, ee);
        }
        float den = 0.f;
#pragma unroll
        for (int e = 0; e < 5; ++e) if (e < dg) { ev[e] = __expf(ev[e]-m); den += ev[e]; }
        const float inv = 1.f/den;
#pragma unroll
        for (int e = 0; e < 5; ++e) if (e < dg) s_alp[(r*5+e)*4 + hh2] = ev[e]*inv;
      }
    }
    __syncthreads();

    // === L3: aggregate + elu + LN (shfl stats) + apply (+res at l==2) ===
    {
      float lg[16], lb[16];
#pragma unroll
      for (int c4 = 0; c4 < 4; ++c4) {
        const float4 g4 = *(const float4*)&ln_g[l*128 + cb + c4*4];
        const float4 b4 = *(const float4*)&ln_b[l*128 + cb + c4*4];
        lg[c4*4+0]=g4.x; lg[c4*4+1]=g4.y; lg[c4*4+2]=g4.z; lg[c4*4+3]=g4.w;
        lb[c4*4+0]=b4.x; lb[c4*4+1]=b4.y; lb[c4*4+2]=b4.z; lb[c4*4+3]=b4.w;
      }
#pragma unroll
      for (int i = 0; i < 3; ++i) {
        const int r = rr[i], j = rj[i], base = r - rj[i];
        const int dg = c_deg[j];
        float ov[16];
#pragma unroll
        for (int c4 = 0; c4 < 4; ++c4) {
          const float4 gb4 = *(const float4*)&gat_b[l*128 + cb + c4*4];
          ov[c4*4+0]=gb4.x; ov[c4*4+1]=gb4.y; ov[c4*4+2]=gb4.z; ov[c4*4+3]=gb4.w;
        }
#pragma unroll
        for (int e = 0; e < 5; ++e) if (e < dg) {
          const float al = s_alp[(r*5+e)*4 + hh];
          const unsigned short* xp = &s_xlb[(base + c_inc[j][e])*HB + cb];
          const short8 xa = *(const short8*)xp;
          const short8 xb = *(const short8*)(xp + 8);
#pragma unroll
          for (int c = 0; c < 8; ++c) {
            ov[c]   += al * bf2f((unsigned short)xa[c]);
            ov[8+c] += al * bf2f((unsigned short)xb[c]);
          }
        }
        float s = 0.f, s2 = 0.f;
#pragma unroll
        for (int c = 0; c < 16; ++c) {
          float v = ov[c];
          v = (v > 0.f) ? v : (__expf(v) - 1.f);   // elu
          ov[c] = v;
          s += v; s2 += v*v;
        }
#pragma unroll
        for (int off = 1; off < 8; off <<= 1) {
          s  += __shfl_xor(s,  off, 64);
          s2 += __shfl_xor(s2, off, 64);
        }
        const float mean = s * (1.f/128.f);
        const float rstd = rsqrtf(s2 * (1.f/128.f) - mean*mean + 1e-5f);

        short8 p0, p1;
        if (l == 2) {  // fold h += res into last layer's apply
          const float* xp = &s_x[rb[i]*72 + rj[i]*3];
          const float x0 = xp[0], x1 = xp[1], x2 = xp[2];
#pragma unroll
          for (int c = 0; c < 16; ++c) {
            const int ch = cb + c;
            float v = (ov[c]-mean)*rstd*lg[c] + lb[c] + vh[i][c];
            v += x0*res_w[ch] + x1*res_w[128+ch] + x2*res_w[256+ch] + res_b[ch];
            vh[i][c] = v;
            if (c < 8) p0[c] = (short)f2bf(v); else p1[c-8] = (short)f2bf(v);
          }
        } else {
#pragma unroll
          for (int c = 0; c < 16; ++c) {
            float v = (ov[c]-mean)*rstd*lg[c] + lb[c];
            if (l > 0) v += vh[i][c];
            vh[i][c] = v;
            if (c < 8) p0[c] = (short)f2bf(v); else p1[c-8] = (short)f2bf(v);
          }
        }
        *(short8*)&s_hb[r*HB + cb]     = p0;
        *(short8*)&s_hb[r*HB + cb + 8] = p1;
      }
    }
    __syncthreads();
  }

  // ---- F1: y1 = relu(h @ w1t + b1) via MFMA (M=96,N=64,K=128), fp32 -> s_y ----
  {
    const unsigned short* W1 = &g_wt[49152];
    const int nt = wv;
    short8 bfr[4];
#pragma unroll
    for (int ks = 0; ks < 4; ++ks)
      bfr[ks] = *(const short8*)&W1[(nt*16 + l16)*128 + ks*32 + q*8];
    const float bv = b1[nt*16 + l16];
    float* s_y = (float*)s_xlb;
#pragma unroll
    for (int mt = 0; mt < 6; ++mt) {
      f32x4 acc = {bv, bv, bv, bv};
#pragma unroll
      for (int ks = 0; ks < 4; ++ks) {
        const short8 a = *(const short8*)&s_hb[(mt*16 + l16)*HB + ks*32 + q*8];
        acc = __builtin_amdgcn_mfma_f32_16x16x32_bf16(a, bfr[ks], acc, 0, 0, 0);
      }
#pragma unroll
      for (int r = 0; r < 4; ++r)
        s_y[(mt*16 + q*4 + r)*YS + nt*16 + l16] = fmaxf(acc[r], 0.f);
    }
  }
  __syncthreads();

  // ---- F2: LN(64) stats + yln -> s_hb (bf16) ----
  if (tid < 192) {
    const int row = tid >> 1, half = tid & 1;
    const float* yr = (const float*)s_xlb + row*YS + half*32;
    float yv[32];
    float s = 0.f, s2 = 0.f;
#pragma unroll
    for (int c4 = 0; c4 < 8; ++c4) {
      const float4 v4 = *(const float4*)&yr[c4*4];
      yv[c4*4+0]=v4.x; yv[c4*4+1]=v4.y; yv[c4*4+2]=v4.z; yv[c4*4+3]=v4.w;
      s += v4.x+v4.y+v4.z+v4.w;
      s2 += v4.x*v4.x + v4.y*v4.y + v4.z*v4.z + v4.w*v4.w;
    }
    s  += __shfl_xor(s,  1, 64);
    s2 += __shfl_xor(s2, 1, 64);
    const float mean = s * (1.f/64.f);
    const float rstd = rsqrtf(s2 * (1.f/64.f) - mean*mean + 1e-5f);
    short8 pk[4];
#pragma unroll
    for (int c = 0; c < 32; ++c) {
      const int m = half*32 + c;
      const float yl = (yv[c]-mean)*rstd*lng2[m] + lnb2[m];
      pk[c >> 3][c & 7] = (short)f2bf(yl);
    }
#pragma unroll
    for (int p = 0; p < 4; ++p)
      *(short8*)&s_hb[row*HB + half*32 + p*8] = pk[p];
  }
  __syncthreads();

  // ---- F3: out = yln @ w2t + b2 via MFMA (M=96,N=6(16),K=64) -> global ----
  {
    const unsigned short* W2 = &g_wt[63488];
    const short8 bf0 = *(const short8*)&W2[l16*64 + q*8];
    const short8 bf1 = *(const short8*)&W2[l16*64 + 32 + q*8];
    const float bv = (l16 < 6) ? b2[l16] : 0.f;
    const int nmt = (wv < 2) ? 2 : 1;
#pragma unroll
    for (int s = 0; s < 2; ++s) if (s < nmt) {
      const int mt = wv + 4*s;
      f32x4 acc = {0.f,0.f,0.f,0.f};
      const short8 a0 = *(const short8*)&s_hb[(mt*16 + l16)*HB + q*8];
      acc = __builtin_amdgcn_mfma_f32_16x16x32_bf16(a0, bf0, acc, 0, 0, 0);
      const short8 a1 = *(const short8*)&s_hb[(mt*16 + l16)*HB + 32 + q*8];
      acc = __builtin_amdgcn_mfma_f32_16x16x32_bf16(a1, bf1, acc, 0, 0, 0);
      if (l16 < 6) {
#pragma unroll
        for (int r = 0; r < 4; ++r) {
          const int row = mt*16 + q*4 + r;
          const int bp = row / 24, j = row - 24*bp;
          out[((long)blockIdx.x*BPB + bp)*144 + j*6 + l16] = acc[r] + bv;
        }
      }
    }
  }
}

extern "C" void kernel_launch(void* const* d_in, const int* in_sizes, int n_in,
                              void* d_out, int out_size, void* d_ws, size_t ws_size,
                              hipStream_t stream) {
  (void)n_in; (void)out_size; (void)d_ws; (void)ws_size;
  const float* x     = (const float*)d_in[0];
  const float* in_w  = (const float*)d_in[1];
  const float* in_b  = (const float*)d_in[2];
  const float* res_w = (const float*)d_in[3];
  const float* res_b = (const float*)d_in[4];
  const float* pos   = (const float*)d_in[5];
  const float* gat_w = (const float*)d_in[6];
  const float* att_s = (const float*)d_in[7];
  const float* att_d = (const float*)d_in[8];
  const float* gat_b = (const float*)d_in[9];
  const float* ln_g  = (const float*)d_in[10];
  const float* ln_b  = (const float*)d_in[11];
  const float* w1    = (const float*)d_in[12];
  const float* b1    = (const float*)d_in[13];
  const float* lng2  = (const float*)d_in[14];
  const float* lnb2  = (const float*)d_in[15];
  const float* w2    = (const float*)d_in[16];
  const float* b2    = (const float*)d_in[17];
  float* out = (float*)d_out;

  const int B = in_sizes[0] / (J*3);
  hipLaunchKernelGGL(prep_weights, dim3((64512 + 255)/256), dim3(256), 0, stream,
                     gat_w, att_s, att_d, w1, w2);
  hipLaunchKernelGGL(gat_fused, dim3(B/BPB), dim3(256), 0, stream,
                     x, in_w, in_b, res_w, res_b, pos, gat_b, ln_g, ln_b,
                     b1, lng2, lnb2, b2, out);
}